// Round 9
// baseline (204.060 us; speedup 1.0000x reference)
//
#include <hip/hip_runtime.h>
#include <hip/hip_bf16.h>

#define CHN 16
#define RF 9
#define HWDIM 256
#define POSN (HWDIM * HWDIM)
#define NBINS 32768   // 5 bits per axis, 3D Morton

typedef _Float16 half2_t __attribute__((ext_vector_type(2)));

__device__ __forceinline__ half2_t u2h(uint32_t u) {
    union { uint32_t u; half2_t h; } x; x.u = u; return x.h;
}
__device__ __forceinline__ uint32_t f2h(float f) {
    union { _Float16 h; uint16_t u; } x; x.h = (_Float16)f; return (uint32_t)x.u;
}
__device__ __forceinline__ float h2f(uint32_t u) {
    union { uint16_t u; _Float16 h; } x; x.u = (uint16_t)u; return (float)x.h;
}

#if __has_builtin(__builtin_amdgcn_fdot2)
__device__ __forceinline__ float DOT2(half2_t a, half2_t b, float c) {
    return __builtin_amdgcn_fdot2(a, b, c, false);
}
#else
__device__ __forceinline__ float DOT2(half2_t a, half2_t b, float c) {
    return fmaf((float)a.x, (float)b.x, fmaf((float)a.y, (float)b.y, c));
}
#endif

// ---------- Morton helpers ----------
__device__ __forceinline__ uint32_t part1by2(uint32_t x) {
    x &= 0x3ffu;
    x = (x | (x << 16)) & 0x030000FFu;
    x = (x | (x << 8))  & 0x0300F00Fu;
    x = (x | (x << 4))  & 0x030C30C3u;
    x = (x | (x << 2))  & 0x09249249u;
    return x;
}
__device__ __forceinline__ uint32_t morton_key(float c0, float c1, float c2) {
    int q0 = min(31, max(0, (int)((c0 + 1.f) * 16.f)));
    int q1 = min(31, max(0, (int)((c1 + 1.f) * 16.f)));
    int q2 = min(31, max(0, (int)((c2 + 1.f) * 16.f)));
    return (part1by2((uint32_t)q0) << 2) | (part1by2((uint32_t)q1) << 1) | part1by2((uint32_t)q2);
}

// ---------- pack: wave-level transpose to f16, NO LDS ----------
// A: [p][pos][cc] uint4 = f16 freqs r0..r7 packed in pairs (16 B per (pos,cc))
// B: [p][pos][cc>>1] u32 = f16 r8 for channel pair (lo=even cc, hi=odd cc)
// One 256-thread block packs 16 consecutive positions: thread = (pos_off = t>>4, cc = t&15).
// A-store: wave's 64 lanes write 1 KB contiguous (fully coalesced).
// Reads: per instr 16 segments x 16B; the block's 4 waves tile complete lines (L1 absorbs).
__device__ __forceinline__ void pack_tile16(int tile,
                                            const float* __restrict__ Pu,
                                            const float* __restrict__ Pv,
                                            const float* __restrict__ Pw,
                                            uint4* __restrict__ A,
                                            uint32_t* __restrict__ B, int t) {
    int p = tile >> 12;                       // POSN/16 = 4096 tiles per plane
    int pos = ((tile & 4095) << 4) + (t >> 4);
    int cc = t & 15;
    const float* P = (p == 0) ? Pu : ((p == 1) ? Pv : Pw);
    const float* Pc = P + (size_t)(cc * RF) * POSN + pos;
    uint32_t w[4];
#pragma unroll
    for (int j = 0; j < 4; ++j) {
        float v0 = Pc[(size_t)(2 * j) * POSN];
        float v1 = Pc[(size_t)(2 * j + 1) * POSN];
        w[j] = f2h(v0) | (f2h(v1) << 16);
    }
    A[((size_t)p * POSN + pos) * CHN + cc] = make_uint4(w[0], w[1], w[2], w[3]);
    uint32_t h8 = f2h(Pc[(size_t)8 * POSN]);
    uint32_t other = __shfl_xor(h8, 1);       // partner channel cc^1 (same pos)
    if (!(cc & 1)) {
        B[((size_t)p * POSN + pos) * 8 + (cc >> 1)] = h8 | (other << 16);
    }
}

// ---------- D1: histogram + pack slice ----------
__global__ __launch_bounds__(256) void fuse_hist(const float* __restrict__ Pu,
                                                 const float* __restrict__ Pv,
                                                 const float* __restrict__ Pw,
                                                 uint4* __restrict__ A,
                                                 uint32_t* __restrict__ B,
                                                 const float* __restrict__ coords,
                                                 uint32_t* __restrict__ hist,
                                                 int N, int npack, int tile_lo) {
    int b = blockIdx.x, t = threadIdx.x;
    if (b < npack) {
        pack_tile16(tile_lo + b, Pu, Pv, Pw, A, B, t);
    } else {
        int n = (b - npack) * 256 + t;
        if (n < N) {
            float c0 = coords[3 * n], c1 = coords[3 * n + 1], c2 = coords[3 * n + 2];
            atomicAdd(&hist[morton_key(c0, c1, c2)], 1u);
        }
    }
}

// ---------- D2: 1-block exclusive scan (hidden under pack slice) ----------
__global__ __launch_bounds__(256) void fuse_scan(const float* __restrict__ Pu,
                                                 const float* __restrict__ Pv,
                                                 const float* __restrict__ Pw,
                                                 uint4* __restrict__ A,
                                                 uint32_t* __restrict__ B,
                                                 uint32_t* __restrict__ hist,
                                                 int npack, int tile_lo) {
    int b = blockIdx.x, t = threadIdx.x;
    if (b == 0) {
        __shared__ uint32_t sh[256];
        const int PER = NBINS / 256;      // 128 bins per thread
        int base = t * PER;
        uint32_t s = 0;
        for (int i = 0; i < PER; ++i) s += hist[base + i];
        sh[t] = s;
        __syncthreads();
        for (int off = 1; off < 256; off <<= 1) {
            uint32_t v = (t >= off) ? sh[t - off] : 0u;
            __syncthreads();
            sh[t] += v;
            __syncthreads();
        }
        uint32_t run = sh[t] - s;         // exclusive prefix of this chunk
        for (int i = 0; i < PER; ++i) {
            uint32_t h = hist[base + i];
            hist[base + i] = run;
            run += h;
        }
    } else {
        pack_tile16(tile_lo + (b - 1), Pu, Pv, Pw, A, B, t);
    }
}

// ---------- D3: scatter + pack slice ----------
__global__ __launch_bounds__(256) void fuse_scatter(const float* __restrict__ Pu,
                                                    const float* __restrict__ Pv,
                                                    const float* __restrict__ Pw,
                                                    uint4* __restrict__ A,
                                                    uint32_t* __restrict__ B,
                                                    const float* __restrict__ coords,
                                                    uint32_t* __restrict__ hist,
                                                    float4* __restrict__ sorted,
                                                    int N, int npack, int tile_lo) {
    int b = blockIdx.x, t = threadIdx.x;
    if (b < npack) {
        pack_tile16(tile_lo + b, Pu, Pv, Pw, A, B, t);
    } else {
        int n = (b - npack) * 256 + t;
        if (n < N) {
            float c0 = coords[3 * n], c1 = coords[3 * n + 1], c2 = coords[3 * n + 2];
            uint32_t key = morton_key(c0, c1, c2);
            uint32_t dst = atomicAdd(&hist[key], 1u);
            sorted[dst] = make_float4(c0, c1, c2, __uint_as_float((uint32_t)n));
        }
    }
}

// ---------- D4: main — EXACT R4 structure (VGPR 36, occupancy ~68%, 83 us) ----------
// 32 points/block, 2 points/thread via outer half-loop (slot, slot+16). meta stride 40.
// meta[pt*40 + p*13 + idx]: [0..3] f16x2 basis r0..7, [4] b8 f32, [5..8] weights f32,
//                           [9..12] corner byte offsets (pos*256)
__global__ __launch_bounds__(256) void triplane_f16v2(const float4* __restrict__ sorted,
                                                      const uint4* __restrict__ A,
                                                      const uint32_t* __restrict__ B,
                                                      float* __restrict__ out, int N, int nblk) {
    __shared__ float4 pts[32];
    __shared__ uint32_t meta[32 * 40];
    int blk = blockIdx.x;
    {   // bijective XCD-chunked swizzle (contiguous Morton range per XCD)
        int q = nblk >> 3, r = nblk & 7;
        int xcd = blk & 7, local = blk >> 3;
        blk = (xcd < r ? xcd * (q + 1) : r * (q + 1) + (xcd - r) * q) + local;
    }
    int base = blk * 32;
    int t = threadIdx.x;
    if (t < 32) {
        int i = base + t;
        pts[t] = (i < N) ? sorted[i] : make_float4(0.f, 0.f, 0.f, __uint_as_float(0u));
    }
    __syncthreads();
    if (t < 128 && (t & 3) < 3) {   // one thread per (point, plane)
        int pt = t >> 2, p = t & 3;
        float4 c = pts[pt];
        float gx = (p == 0) ? c.y : c.x;
        float gy = (p == 2) ? c.y : c.z;
        float ci = (p == 0) ? c.x : ((p == 1) ? c.y : c.z);
        float ix = (gx + 1.f) * 127.5f;
        float iy = (gy + 1.f) * 127.5f;
        float x0f = floorf(ix), y0f = floorf(iy);
        float wx = ix - x0f, wy = iy - y0f;
        int x0 = min(max((int)x0f, 0), HWDIM - 1);
        int y0 = min(max((int)y0f, 0), HWDIM - 1);
        int x1 = min(x0 + 1, HWDIM - 1);
        int y1 = min(y0 + 1, HWDIM - 1);
        uint32_t* m = &meta[pt * 40 + p * 13];
        float cv = (ci + 1.f) * 127.5f + 0.5f;
        float bb[9];
#pragma unroll
        for (int r = 0; r < 9; ++r) {
            const float k = 3.14159265358979f * ((float)(1 << r) - 0.5f) * (1.f / 512.f);
            bb[r] = __cosf(cv * k);
        }
#pragma unroll
        for (int j = 0; j < 4; ++j) m[j] = f2h(bb[2 * j]) | (f2h(bb[2 * j + 1]) << 16);
        m[4] = __float_as_uint(bb[8]);
        m[5] = __float_as_uint((1.f - wx) * (1.f - wy));
        m[6] = __float_as_uint(wx * (1.f - wy));
        m[7] = __float_as_uint((1.f - wx) * wy);
        m[8] = __float_as_uint(wx * wy);
        m[9]  = (uint32_t)(y0 * HWDIM + x0) * 256u;
        m[10] = (uint32_t)(y0 * HWDIM + x1) * 256u;
        m[11] = (uint32_t)(y1 * HWDIM + x0) * 256u;
        m[12] = (uint32_t)(y1 * HWDIM + x1) * 256u;
    }
    __syncthreads();
    int cc = t & 15, slot = t >> 4;
    const char* Ab = (const char*)A;
    const char* Bb = (const char*)B;
    const uint32_t bofs = ((uint32_t)(cc >> 1) << 2);
#pragma unroll
    for (int half = 0; half < 2; ++half) {
        int pt = slot + half * 16;
        int gi = base + pt;
        float acc = 0.f;
#pragma unroll
        for (int p = 0; p < 3; ++p) {
            const uint32_t* m = &meta[pt * 40 + p * 13];
            half2_t b01 = u2h(m[0]), b23 = u2h(m[1]), b45 = u2h(m[2]), b67 = u2h(m[3]);
            float b8 = __uint_as_float(m[4]);
            const char* Apl = Ab + (size_t)p * ((size_t)POSN * 256);
            const char* Bpl = Bb + (size_t)p * ((size_t)POSN * 32);
            float ps = 0.f;
#pragma unroll
            for (int k = 0; k < 4; ++k) {
                uint32_t ob = m[9 + k];
                uint4 a = *(const uint4*)(Apl + ob + cc * 16);    // 16 lanes read 256B contiguous
                uint32_t bw = *(const uint32_t*)(Bpl + (ob >> 3) + bofs);
                float v8 = h2f((cc & 1) ? (bw >> 16) : (bw & 0xffffu));
                float s = b8 * v8;
                s = DOT2(u2h(a.x), b01, s);
                s = DOT2(u2h(a.y), b23, s);
                s = DOT2(u2h(a.z), b45, s);
                s = DOT2(u2h(a.w), b67, s);
                ps = fmaf(__uint_as_float(m[5 + k]), s, ps);
            }
            acc += ps;
        }
        if (gi < N) {
            uint32_t n = __float_as_uint(pts[pt].w);
            out[(size_t)n * CHN + cc] = 2.f * acc;
        }
    }
}

// ---------- fallback: direct gather from (C,H,W) f32 ----------
__global__ __launch_bounds__(256) void triplane_direct(const float* __restrict__ coords,
                                                       const float* __restrict__ Pu,
                                                       const float* __restrict__ Pv,
                                                       const float* __restrict__ Pw,
                                                       float* __restrict__ out, int N) {
    int tid = blockIdx.x * blockDim.x + threadIdx.x;
    int n = tid >> 4;
    if (n >= N) return;
    int cc = tid & 15;
    float c0 = coords[3 * n + 0];
    float c1 = coords[3 * n + 1];
    float c2 = coords[3 * n + 2];
    float acc = 0.f;
#pragma unroll
    for (int p = 0; p < 3; ++p) {
        const float* P = (p == 0) ? Pu : ((p == 1) ? Pv : Pw);
        float gx = (p == 0) ? c1 : c0;
        float gy = (p == 2) ? c1 : c2;
        float ci = (p == 0) ? c0 : ((p == 1) ? c1 : c2);
        float ix = (gx + 1.f) * 127.5f;
        float iy = (gy + 1.f) * 127.5f;
        float x0f = floorf(ix), y0f = floorf(iy);
        float wx = ix - x0f, wy = iy - y0f;
        int x0 = min(max((int)x0f, 0), HWDIM - 1);
        int y0 = min(max((int)y0f, 0), HWDIM - 1);
        int x1 = min(x0 + 1, HWDIM - 1);
        int y1 = min(y0 + 1, HWDIM - 1);
        float cv = (ci + 1.f) * 127.5f + 0.5f;
        float w00 = (1.f - wx) * (1.f - wy), w01 = wx * (1.f - wy);
        float w10 = (1.f - wx) * wy, w11 = wx * wy;
        int p00 = y0 * HWDIM + x0, p01 = y0 * HWDIM + x1;
        int p10 = y1 * HWDIM + x0, p11 = y1 * HWDIM + x1;
#pragma unroll
        for (int r = 0; r < RF; ++r) {
            const float k = 3.14159265358979f * ((float)(1 << r) - 0.5f) / 512.f;
            float b = __cosf(cv * k);
            const float* Pc = P + (size_t)(cc * RF + r) * POSN;
            float v = w00 * Pc[p00] + w01 * Pc[p01] + w10 * Pc[p10] + w11 * Pc[p11];
            acc = fmaf(b, v, acc);
        }
    }
    out[(size_t)n * CHN + cc] = 2.f * acc;
}

extern "C" void kernel_launch(void* const* d_in, const int* in_sizes, int n_in,
                              void* d_out, int out_size, void* d_ws, size_t ws_size,
                              hipStream_t stream) {
    const float* coords = (const float*)d_in[0];
    const float* Pu = (const float*)d_in[1];
    const float* Pv = (const float*)d_in[2];
    const float* Pw = (const float*)d_in[3];
    float* out = (float*)d_out;
    int N = in_sizes[0] / 3;

    size_t offA = 0;
    size_t szA = (size_t)3 * POSN * CHN * sizeof(uint4);        // 48 MB
    size_t offB = offA + szA;
    size_t szB = (size_t)3 * POSN * 8 * sizeof(uint32_t);       // 6 MB
    size_t offS = offB + szB;
    size_t szS = (size_t)N * sizeof(float4);                    // 8 MB @ N=524288
    size_t offH = offS + szS;
    size_t szH = (size_t)NBINS * sizeof(uint32_t);              // 128 KB
    size_t need = offH + szH;

    if (ws_size >= need) {
        char* ws = (char*)d_ws;
        uint4* A = (uint4*)(ws + offA);
        uint32_t* B = (uint32_t*)(ws + offB);
        float4* sorted = (float4*)(ws + offS);
        uint32_t* hist = (uint32_t*)(ws + offH);

        int tblk = (3 * POSN) / 16;                  // 12288 pack tiles (16 pos each)
        int s1 = tblk / 3;                           // 4096
        int s2 = tblk / 3;                           // 4096
        int s3 = tblk - s1 - s2;                     // 4096
        int hblk = (N + 255) / 256;                  // 2048

        hipMemsetAsync(hist, 0, szH, stream);
        fuse_hist<<<s1 + hblk, 256, 0, stream>>>(Pu, Pv, Pw, A, B, coords, hist, N, s1, 0);
        fuse_scan<<<1 + s2, 256, 0, stream>>>(Pu, Pv, Pw, A, B, hist, s2, s1);
        fuse_scatter<<<s3 + hblk, 256, 0, stream>>>(Pu, Pv, Pw, A, B, coords, hist, sorted,
                                                    N, s3, s1 + s2);
        int nblk = (N + 31) / 32;                    // 16384
        triplane_f16v2<<<nblk, 256, 0, stream>>>(sorted, A, B, out, N, nblk);
    } else {
        int threads = N * CHN;
        triplane_direct<<<(threads + 255) / 256, 256, 0, stream>>>(coords, Pu, Pv, Pw, out, N);
    }
}

// Round 10
// 173.050 us; speedup vs baseline: 1.1792x; 1.1792x over previous
//
#include <hip/hip_runtime.h>
#include <hip/hip_bf16.h>

#define CHN 16
#define RF 9
#define HWDIM 256
#define POSN (HWDIM * HWDIM)
#define NBINS 32768   // 5 bits per axis, 3D Morton

typedef _Float16 half2_t __attribute__((ext_vector_type(2)));

__device__ __forceinline__ half2_t u2h(uint32_t u) {
    union { uint32_t u; half2_t h; } x; x.u = u; return x.h;
}
__device__ __forceinline__ uint32_t f2h(float f) {
    union { _Float16 h; uint16_t u; } x; x.h = (_Float16)f; return (uint32_t)x.u;
}
__device__ __forceinline__ float h2f(uint32_t u) {
    union { uint16_t u; _Float16 h; } x; x.u = (uint16_t)u; return (float)x.h;
}

#if __has_builtin(__builtin_amdgcn_fdot2)
__device__ __forceinline__ float DOT2(half2_t a, half2_t b, float c) {
    return __builtin_amdgcn_fdot2(a, b, c, false);
}
#else
__device__ __forceinline__ float DOT2(half2_t a, half2_t b, float c) {
    return fmaf((float)a.x, (float)b.x, fmaf((float)a.y, (float)b.y, c));
}
#endif

// ---------- Morton helpers ----------
__device__ __forceinline__ uint32_t part1by2(uint32_t x) {
    x &= 0x3ffu;
    x = (x | (x << 16)) & 0x030000FFu;
    x = (x | (x << 8))  & 0x0300F00Fu;
    x = (x | (x << 4))  & 0x030C30C3u;
    x = (x | (x << 2))  & 0x09249249u;
    return x;
}
__device__ __forceinline__ uint32_t morton_key(float c0, float c1, float c2) {
    int q0 = min(31, max(0, (int)((c0 + 1.f) * 16.f)));
    int q1 = min(31, max(0, (int)((c1 + 1.f) * 16.f)));
    int q2 = min(31, max(0, (int)((c2 + 1.f) * 16.f)));
    return (part1by2((uint32_t)q0) << 2) | (part1by2((uint32_t)q1) << 1) | part1by2((uint32_t)q2);
}

// ---------- pack one 128-pos tile with 256 threads (LDS-staged transpose to f16) ----------
// A: [p][pos][cc] uint4 = f16 freqs r0..r7 packed in pairs (16 B per (pos,cc))
// B: [p][pos][cc>>1] u32 = f16 r8 for channel pair (lo=even cc, hi=odd cc)
// Threads: pos = t&127 (lane-contiguous -> coalesced 256B reads), cc-half = t>>7.
// 39 KB LDS -> 4 blocks/CU -> 16 waves/CU (2x the 128-thread version).
__device__ __forceinline__ void pack_tile(int tile,
                                          const float* __restrict__ Pu,
                                          const float* __restrict__ Pv,
                                          const float* __restrict__ Pw,
                                          uint4* __restrict__ A,
                                          uint32_t* __restrict__ B,
                                          int t, uint4* LA, uint32_t* LB) {
    int p = tile >> 9;                      // POSN/128 = 512 tiles per plane
    int pos_base = (tile & 511) * 128;
    int pos = t & 127;
    int ch = (t >> 7) * 8;                  // this thread packs cc = ch..ch+7
    const float* P = (p == 0) ? Pu : ((p == 1) ? Pv : Pw);
    const float* Pc0 = P + pos_base + pos;
    uint32_t r8 = 0;
#pragma unroll
    for (int c = 0; c < 8; ++c) {
        int cc = ch + c;
        const float* Pc = Pc0 + (size_t)(cc * RF) * POSN;   // lanes contiguous over pos
        uint32_t w[4];
#pragma unroll
        for (int j = 0; j < 4; ++j) {
            float v0 = Pc[(size_t)(2 * j) * POSN];
            float v1 = Pc[(size_t)(2 * j + 1) * POSN];
            w[j] = f2h(v0) | (f2h(v1) << 16);
        }
        LA[pos * 17 + cc] = make_uint4(w[0], w[1], w[2], w[3]);
        uint32_t h8 = f2h(Pc[(size_t)8 * POSN]);
        if (c & 1) { r8 |= (h8 << 16); LB[pos * 9 + (cc >> 1)] = r8; }
        else r8 = h8;
    }
    __syncthreads();
    // linear dump: fully coalesced global stores
    uint4* Aout = A + ((size_t)p * POSN + pos_base) * CHN;
#pragma unroll
    for (int it = 0; it < 8; ++it) {
        int i = it * 256 + t;                         // 2048 uint4
        Aout[i] = LA[(i >> 4) * 17 + (i & 15)];
    }
    uint32_t* Bout = B + ((size_t)p * POSN + pos_base) * 8;
#pragma unroll
    for (int it = 0; it < 4; ++it) {
        int i = it * 256 + t;                         // 1024 words
        Bout[i] = LB[(i >> 3) * 9 + (i & 7)];
    }
}

// ---------- D1: histogram + pack slice ----------
__global__ __launch_bounds__(256) void fuse_hist(const float* __restrict__ Pu,
                                                 const float* __restrict__ Pv,
                                                 const float* __restrict__ Pw,
                                                 uint4* __restrict__ A,
                                                 uint32_t* __restrict__ B,
                                                 const float* __restrict__ coords,
                                                 uint32_t* __restrict__ hist,
                                                 int N, int npack, int tile_lo) {
    __shared__ uint4 LA[128 * 17];
    __shared__ uint32_t LB[128 * 9];
    int b = blockIdx.x, t = threadIdx.x;
    if (b < npack) {
        pack_tile(tile_lo + b, Pu, Pv, Pw, A, B, t, LA, LB);
    } else {
        int n = (b - npack) * 256 + t;
        if (n < N) {
            float c0 = coords[3 * n], c1 = coords[3 * n + 1], c2 = coords[3 * n + 2];
            atomicAdd(&hist[morton_key(c0, c1, c2)], 1u);
        }
    }
}

// ---------- D2: 1-block exclusive scan (hidden under pack slice) ----------
__global__ __launch_bounds__(256) void fuse_scan(const float* __restrict__ Pu,
                                                 const float* __restrict__ Pv,
                                                 const float* __restrict__ Pw,
                                                 uint4* __restrict__ A,
                                                 uint32_t* __restrict__ B,
                                                 uint32_t* __restrict__ hist,
                                                 int npack, int tile_lo) {
    __shared__ uint4 LA[128 * 17];
    __shared__ uint32_t LB[128 * 9];
    int b = blockIdx.x, t = threadIdx.x;
    if (b == 0) {
        __shared__ uint32_t sh[256];
        const int PER = NBINS / 256;      // 128 bins per thread
        int base = t * PER;
        uint32_t s = 0;
        for (int i = 0; i < PER; ++i) s += hist[base + i];
        sh[t] = s;
        __syncthreads();
        for (int off = 1; off < 256; off <<= 1) {
            uint32_t v = (t >= off) ? sh[t - off] : 0u;
            __syncthreads();
            sh[t] += v;
            __syncthreads();
        }
        uint32_t run = sh[t] - s;         // exclusive prefix of this chunk
        for (int i = 0; i < PER; ++i) {
            uint32_t h = hist[base + i];
            hist[base + i] = run;
            run += h;
        }
    } else {
        pack_tile(tile_lo + (b - 1), Pu, Pv, Pw, A, B, t, LA, LB);
    }
}

// ---------- D3: scatter + pack slice ----------
__global__ __launch_bounds__(256) void fuse_scatter(const float* __restrict__ Pu,
                                                    const float* __restrict__ Pv,
                                                    const float* __restrict__ Pw,
                                                    uint4* __restrict__ A,
                                                    uint32_t* __restrict__ B,
                                                    const float* __restrict__ coords,
                                                    uint32_t* __restrict__ hist,
                                                    float4* __restrict__ sorted,
                                                    int N, int npack, int tile_lo) {
    __shared__ uint4 LA[128 * 17];
    __shared__ uint32_t LB[128 * 9];
    int b = blockIdx.x, t = threadIdx.x;
    if (b < npack) {
        pack_tile(tile_lo + b, Pu, Pv, Pw, A, B, t, LA, LB);
    } else {
        int n = (b - npack) * 256 + t;
        if (n < N) {
            float c0 = coords[3 * n], c1 = coords[3 * n + 1], c2 = coords[3 * n + 2];
            uint32_t key = morton_key(c0, c1, c2);
            uint32_t dst = atomicAdd(&hist[key], 1u);
            sorted[dst] = make_float4(c0, c1, c2, __uint_as_float((uint32_t)n));
        }
    }
}

// ---------- D4: main — EXACT R4 structure (VGPR 36, occupancy ~68%, 83-84 us) ----------
// 32 points/block, 2 points/thread via outer half-loop (slot, slot+16). meta stride 40.
// meta[pt*40 + p*13 + idx]: [0..3] f16x2 basis r0..7, [4] b8 f32, [5..8] weights f32,
//                           [9..12] corner byte offsets (pos*256)
__global__ __launch_bounds__(256) void triplane_f16v2(const float4* __restrict__ sorted,
                                                      const uint4* __restrict__ A,
                                                      const uint32_t* __restrict__ B,
                                                      float* __restrict__ out, int N, int nblk) {
    __shared__ float4 pts[32];
    __shared__ uint32_t meta[32 * 40];
    int blk = blockIdx.x;
    {   // bijective XCD-chunked swizzle (contiguous Morton range per XCD)
        int q = nblk >> 3, r = nblk & 7;
        int xcd = blk & 7, local = blk >> 3;
        blk = (xcd < r ? xcd * (q + 1) : r * (q + 1) + (xcd - r) * q) + local;
    }
    int base = blk * 32;
    int t = threadIdx.x;
    if (t < 32) {
        int i = base + t;
        pts[t] = (i < N) ? sorted[i] : make_float4(0.f, 0.f, 0.f, __uint_as_float(0u));
    }
    __syncthreads();
    if (t < 128 && (t & 3) < 3) {   // one thread per (point, plane)
        int pt = t >> 2, p = t & 3;
        float4 c = pts[pt];
        float gx = (p == 0) ? c.y : c.x;
        float gy = (p == 2) ? c.y : c.z;
        float ci = (p == 0) ? c.x : ((p == 1) ? c.y : c.z);
        float ix = (gx + 1.f) * 127.5f;
        float iy = (gy + 1.f) * 127.5f;
        float x0f = floorf(ix), y0f = floorf(iy);
        float wx = ix - x0f, wy = iy - y0f;
        int x0 = min(max((int)x0f, 0), HWDIM - 1);
        int y0 = min(max((int)y0f, 0), HWDIM - 1);
        int x1 = min(x0 + 1, HWDIM - 1);
        int y1 = min(y0 + 1, HWDIM - 1);
        uint32_t* m = &meta[pt * 40 + p * 13];
        float cv = (ci + 1.f) * 127.5f + 0.5f;
        float bb[9];
#pragma unroll
        for (int r = 0; r < 9; ++r) {
            const float k = 3.14159265358979f * ((float)(1 << r) - 0.5f) * (1.f / 512.f);
            bb[r] = __cosf(cv * k);
        }
#pragma unroll
        for (int j = 0; j < 4; ++j) m[j] = f2h(bb[2 * j]) | (f2h(bb[2 * j + 1]) << 16);
        m[4] = __float_as_uint(bb[8]);
        m[5] = __float_as_uint((1.f - wx) * (1.f - wy));
        m[6] = __float_as_uint(wx * (1.f - wy));
        m[7] = __float_as_uint((1.f - wx) * wy);
        m[8] = __float_as_uint(wx * wy);
        m[9]  = (uint32_t)(y0 * HWDIM + x0) * 256u;
        m[10] = (uint32_t)(y0 * HWDIM + x1) * 256u;
        m[11] = (uint32_t)(y1 * HWDIM + x0) * 256u;
        m[12] = (uint32_t)(y1 * HWDIM + x1) * 256u;
    }
    __syncthreads();
    int cc = t & 15, slot = t >> 4;
    const char* Ab = (const char*)A;
    const char* Bb = (const char*)B;
    const uint32_t bofs = ((uint32_t)(cc >> 1) << 2);
#pragma unroll
    for (int half = 0; half < 2; ++half) {
        int pt = slot + half * 16;
        int gi = base + pt;
        float acc = 0.f;
#pragma unroll
        for (int p = 0; p < 3; ++p) {
            const uint32_t* m = &meta[pt * 40 + p * 13];
            half2_t b01 = u2h(m[0]), b23 = u2h(m[1]), b45 = u2h(m[2]), b67 = u2h(m[3]);
            float b8 = __uint_as_float(m[4]);
            const char* Apl = Ab + (size_t)p * ((size_t)POSN * 256);
            const char* Bpl = Bb + (size_t)p * ((size_t)POSN * 32);
            float ps = 0.f;
#pragma unroll
            for (int k = 0; k < 4; ++k) {
                uint32_t ob = m[9 + k];
                uint4 a = *(const uint4*)(Apl + ob + cc * 16);    // 16 lanes read 256B contiguous
                uint32_t bw = *(const uint32_t*)(Bpl + (ob >> 3) + bofs);
                float v8 = h2f((cc & 1) ? (bw >> 16) : (bw & 0xffffu));
                float s = b8 * v8;
                s = DOT2(u2h(a.x), b01, s);
                s = DOT2(u2h(a.y), b23, s);
                s = DOT2(u2h(a.z), b45, s);
                s = DOT2(u2h(a.w), b67, s);
                ps = fmaf(__uint_as_float(m[5 + k]), s, ps);
            }
            acc += ps;
        }
        if (gi < N) {
            uint32_t n = __float_as_uint(pts[pt].w);
            out[(size_t)n * CHN + cc] = 2.f * acc;
        }
    }
}

// ---------- fallback: direct gather from (C,H,W) f32 ----------
__global__ __launch_bounds__(256) void triplane_direct(const float* __restrict__ coords,
                                                       const float* __restrict__ Pu,
                                                       const float* __restrict__ Pv,
                                                       const float* __restrict__ Pw,
                                                       float* __restrict__ out, int N) {
    int tid = blockIdx.x * blockDim.x + threadIdx.x;
    int n = tid >> 4;
    if (n >= N) return;
    int cc = tid & 15;
    float c0 = coords[3 * n + 0];
    float c1 = coords[3 * n + 1];
    float c2 = coords[3 * n + 2];
    float acc = 0.f;
#pragma unroll
    for (int p = 0; p < 3; ++p) {
        const float* P = (p == 0) ? Pu : ((p == 1) ? Pv : Pw);
        float gx = (p == 0) ? c1 : c0;
        float gy = (p == 2) ? c1 : c2;
        float ci = (p == 0) ? c0 : ((p == 1) ? c1 : c2);
        float ix = (gx + 1.f) * 127.5f;
        float iy = (gy + 1.f) * 127.5f;
        float x0f = floorf(ix), y0f = floorf(iy);
        float wx = ix - x0f, wy = iy - y0f;
        int x0 = min(max((int)x0f, 0), HWDIM - 1);
        int y0 = min(max((int)y0f, 0), HWDIM - 1);
        int x1 = min(x0 + 1, HWDIM - 1);
        int y1 = min(y0 + 1, HWDIM - 1);
        float cv = (ci + 1.f) * 127.5f + 0.5f;
        float w00 = (1.f - wx) * (1.f - wy), w01 = wx * (1.f - wy);
        float w10 = (1.f - wx) * wy, w11 = wx * wy;
        int p00 = y0 * HWDIM + x0, p01 = y0 * HWDIM + x1;
        int p10 = y1 * HWDIM + x0, p11 = y1 * HWDIM + x1;
#pragma unroll
        for (int r = 0; r < RF; ++r) {
            const float k = 3.14159265358979f * ((float)(1 << r) - 0.5f) / 512.f;
            float b = __cosf(cv * k);
            const float* Pc = P + (size_t)(cc * RF + r) * POSN;
            float v = w00 * Pc[p00] + w01 * Pc[p01] + w10 * Pc[p10] + w11 * Pc[p11];
            acc = fmaf(b, v, acc);
        }
    }
    out[(size_t)n * CHN + cc] = 2.f * acc;
}

extern "C" void kernel_launch(void* const* d_in, const int* in_sizes, int n_in,
                              void* d_out, int out_size, void* d_ws, size_t ws_size,
                              hipStream_t stream) {
    const float* coords = (const float*)d_in[0];
    const float* Pu = (const float*)d_in[1];
    const float* Pv = (const float*)d_in[2];
    const float* Pw = (const float*)d_in[3];
    float* out = (float*)d_out;
    int N = in_sizes[0] / 3;

    size_t offA = 0;
    size_t szA = (size_t)3 * POSN * CHN * sizeof(uint4);        // 48 MB
    size_t offB = offA + szA;
    size_t szB = (size_t)3 * POSN * 8 * sizeof(uint32_t);       // 6 MB
    size_t offS = offB + szB;
    size_t szS = (size_t)N * sizeof(float4);                    // 8 MB @ N=524288
    size_t offH = offS + szS;
    size_t szH = (size_t)NBINS * sizeof(uint32_t);              // 128 KB
    size_t need = offH + szH;

    if (ws_size >= need) {
        char* ws = (char*)d_ws;
        uint4* A = (uint4*)(ws + offA);
        uint32_t* B = (uint32_t*)(ws + offB);
        float4* sorted = (float4*)(ws + offS);
        uint32_t* hist = (uint32_t*)(ws + offH);

        int tblk = (3 * POSN) / 128;                 // 1536 pack tiles (128 pos each)
        int s1 = tblk / 3;                           // 512
        int s2 = tblk / 3;                           // 512
        int s3 = tblk - s1 - s2;                     // 512
        int hblk = (N + 255) / 256;                  // 2048

        hipMemsetAsync(hist, 0, szH, stream);
        fuse_hist<<<s1 + hblk, 256, 0, stream>>>(Pu, Pv, Pw, A, B, coords, hist, N, s1, 0);
        fuse_scan<<<1 + s2, 256, 0, stream>>>(Pu, Pv, Pw, A, B, hist, s2, s1);
        fuse_scatter<<<s3 + hblk, 256, 0, stream>>>(Pu, Pv, Pw, A, B, coords, hist, sorted,
                                                    N, s3, s1 + s2);
        int nblk = (N + 31) / 32;                    // 16384
        triplane_f16v2<<<nblk, 256, 0, stream>>>(sorted, A, B, out, N, nblk);
    } else {
        int threads = N * CHN;
        triplane_direct<<<(threads + 255) / 256, 256, 0, stream>>>(coords, Pu, Pv, Pw, out, N);
    }
}

// Round 11
// 170.965 us; speedup vs baseline: 1.1936x; 1.0122x over previous
//
#include <hip/hip_runtime.h>
#include <hip/hip_bf16.h>

#define CHN 16
#define RF 9
#define HWDIM 256
#define POSN (HWDIM * HWDIM)
#define NBINS 32768   // 5 bits per axis, 3D Morton
#define TPOS 64       // positions per pack tile

typedef _Float16 half2_t __attribute__((ext_vector_type(2)));

__device__ __forceinline__ half2_t u2h(uint32_t u) {
    union { uint32_t u; half2_t h; } x; x.u = u; return x.h;
}
__device__ __forceinline__ uint32_t f2h(float f) {
    union { _Float16 h; uint16_t u; } x; x.h = (_Float16)f; return (uint32_t)x.u;
}
__device__ __forceinline__ float h2f(uint32_t u) {
    union { uint16_t u; _Float16 h; } x; x.u = (uint16_t)u; return (float)x.h;
}

#if __has_builtin(__builtin_amdgcn_fdot2)
__device__ __forceinline__ float DOT2(half2_t a, half2_t b, float c) {
    return __builtin_amdgcn_fdot2(a, b, c, false);
}
#else
__device__ __forceinline__ float DOT2(half2_t a, half2_t b, float c) {
    return fmaf((float)a.x, (float)b.x, fmaf((float)a.y, (float)b.y, c));
}
#endif

// ---------- Morton helpers ----------
__device__ __forceinline__ uint32_t part1by2(uint32_t x) {
    x &= 0x3ffu;
    x = (x | (x << 16)) & 0x030000FFu;
    x = (x | (x << 8))  & 0x0300F00Fu;
    x = (x | (x << 4))  & 0x030C30C3u;
    x = (x | (x << 2))  & 0x09249249u;
    return x;
}
__device__ __forceinline__ uint32_t morton_key(float c0, float c1, float c2) {
    int q0 = min(31, max(0, (int)((c0 + 1.f) * 16.f)));
    int q1 = min(31, max(0, (int)((c1 + 1.f) * 16.f)));
    int q2 = min(31, max(0, (int)((c2 + 1.f) * 16.f)));
    return (part1by2((uint32_t)q0) << 2) | (part1by2((uint32_t)q1) << 1) | part1by2((uint32_t)q2);
}

// ---------- pack one 64-pos tile with 256 threads (LDS-staged transpose to f16) ----------
// A: [p][pos][cc] uint4 = f16 freqs r0..r7 packed in pairs (16 B per (pos,cc))
// B: [p][pos][cc>>1] u32 = f16 r8 for channel pair (lo=even cc, hi=odd cc)
// Threads: pos = t&63 (lane-contiguous -> coalesced 256B reads), 4 channels each.
// LDS 19.7 KB -> 8 blocks/CU cap; 1024-block slices -> 4 blocks/CU = 16 waves/CU.
__device__ __forceinline__ void pack_tile64(int tile,
                                            const float* __restrict__ Pu,
                                            const float* __restrict__ Pv,
                                            const float* __restrict__ Pw,
                                            uint4* __restrict__ A,
                                            uint32_t* __restrict__ B,
                                            int t, uint4* LA, uint32_t* LB) {
    int p = tile >> 10;                     // POSN/64 = 1024 tiles per plane
    int pos_base = (tile & 1023) * TPOS;
    int pos = t & 63;
    int ch = (t >> 6) * 4;                  // this thread packs cc = ch..ch+3
    const float* P = (p == 0) ? Pu : ((p == 1) ? Pv : Pw);
    const float* Pc0 = P + pos_base + pos;
    uint32_t r8 = 0;
#pragma unroll
    for (int c = 0; c < 4; ++c) {
        int cc = ch + c;
        const float* Pc = Pc0 + (size_t)(cc * RF) * POSN;   // lanes contiguous over pos
        uint32_t w[4];
#pragma unroll
        for (int j = 0; j < 4; ++j) {
            float v0 = Pc[(size_t)(2 * j) * POSN];
            float v1 = Pc[(size_t)(2 * j + 1) * POSN];
            w[j] = f2h(v0) | (f2h(v1) << 16);
        }
        LA[pos * 17 + cc] = make_uint4(w[0], w[1], w[2], w[3]);
        uint32_t h8 = f2h(Pc[(size_t)8 * POSN]);
        if (c & 1) LB[pos * 9 + (cc >> 1)] = r8 | (h8 << 16);
        else r8 = h8;
    }
    __syncthreads();
    // linear dump: fully coalesced global stores
    uint4* Aout = A + ((size_t)p * POSN + pos_base) * CHN;
#pragma unroll
    for (int it = 0; it < 4; ++it) {
        int i = it * 256 + t;                         // 1024 uint4
        Aout[i] = LA[(i >> 4) * 17 + (i & 15)];
    }
    uint32_t* Bout = B + ((size_t)p * POSN + pos_base) * 8;
#pragma unroll
    for (int it = 0; it < 2; ++it) {
        int i = it * 256 + t;                         // 512 words
        Bout[i] = LB[(i >> 3) * 9 + (i & 7)];
    }
}

// ---------- D1: histogram + pack slice ----------
__global__ __launch_bounds__(256) void fuse_hist(const float* __restrict__ Pu,
                                                 const float* __restrict__ Pv,
                                                 const float* __restrict__ Pw,
                                                 uint4* __restrict__ A,
                                                 uint32_t* __restrict__ B,
                                                 const float* __restrict__ coords,
                                                 uint32_t* __restrict__ hist,
                                                 int N, int npack, int tile_lo) {
    __shared__ uint4 LA[TPOS * 17];
    __shared__ uint32_t LB[TPOS * 9];
    int b = blockIdx.x, t = threadIdx.x;
    if (b < npack) {
        pack_tile64(tile_lo + b, Pu, Pv, Pw, A, B, t, LA, LB);
    } else {
        int n = (b - npack) * 256 + t;
        if (n < N) {
            float c0 = coords[3 * n], c1 = coords[3 * n + 1], c2 = coords[3 * n + 2];
            atomicAdd(&hist[morton_key(c0, c1, c2)], 1u);
        }
    }
}

// ---------- D2: 1-block exclusive scan (hidden under pack slice) ----------
__global__ __launch_bounds__(256) void fuse_scan(const float* __restrict__ Pu,
                                                 const float* __restrict__ Pv,
                                                 const float* __restrict__ Pw,
                                                 uint4* __restrict__ A,
                                                 uint32_t* __restrict__ B,
                                                 uint32_t* __restrict__ hist,
                                                 int npack, int tile_lo) {
    __shared__ uint4 LA[TPOS * 17];
    __shared__ uint32_t LB[TPOS * 9];
    int b = blockIdx.x, t = threadIdx.x;
    if (b == 0) {
        __shared__ uint32_t sh[256];
        const int PER = NBINS / 256;      // 128 bins per thread
        int base = t * PER;
        uint32_t s = 0;
        for (int i = 0; i < PER; ++i) s += hist[base + i];
        sh[t] = s;
        __syncthreads();
        for (int off = 1; off < 256; off <<= 1) {
            uint32_t v = (t >= off) ? sh[t - off] : 0u;
            __syncthreads();
            sh[t] += v;
            __syncthreads();
        }
        uint32_t run = sh[t] - s;         // exclusive prefix of this chunk
        for (int i = 0; i < PER; ++i) {
            uint32_t h = hist[base + i];
            hist[base + i] = run;
            run += h;
        }
    } else {
        pack_tile64(tile_lo + (b - 1), Pu, Pv, Pw, A, B, t, LA, LB);
    }
}

// ---------- D3: scatter + pack slice ----------
__global__ __launch_bounds__(256) void fuse_scatter(const float* __restrict__ Pu,
                                                    const float* __restrict__ Pv,
                                                    const float* __restrict__ Pw,
                                                    uint4* __restrict__ A,
                                                    uint32_t* __restrict__ B,
                                                    const float* __restrict__ coords,
                                                    uint32_t* __restrict__ hist,
                                                    float4* __restrict__ sorted,
                                                    int N, int npack, int tile_lo) {
    __shared__ uint4 LA[TPOS * 17];
    __shared__ uint32_t LB[TPOS * 9];
    int b = blockIdx.x, t = threadIdx.x;
    if (b < npack) {
        pack_tile64(tile_lo + b, Pu, Pv, Pw, A, B, t, LA, LB);
    } else {
        int n = (b - npack) * 256 + t;
        if (n < N) {
            float c0 = coords[3 * n], c1 = coords[3 * n + 1], c2 = coords[3 * n + 2];
            uint32_t key = morton_key(c0, c1, c2);
            uint32_t dst = atomicAdd(&hist[key], 1u);
            sorted[dst] = make_float4(c0, c1, c2, __uint_as_float((uint32_t)n));
        }
    }
}

// ---------- D4: main — EXACT R4 structure (VGPR 36, occupancy ~68%, 84 us) ----------
// 32 points/block, 2 points/thread via outer half-loop (slot, slot+16). meta stride 40.
// meta[pt*40 + p*13 + idx]: [0..3] f16x2 basis r0..7, [4] b8 f32, [5..8] weights f32,
//                           [9..12] corner byte offsets (pos*256)
__global__ __launch_bounds__(256) void triplane_f16v2(const float4* __restrict__ sorted,
                                                      const uint4* __restrict__ A,
                                                      const uint32_t* __restrict__ B,
                                                      float* __restrict__ out, int N, int nblk) {
    __shared__ float4 pts[32];
    __shared__ uint32_t meta[32 * 40];
    int blk = blockIdx.x;
    {   // bijective XCD-chunked swizzle (contiguous Morton range per XCD)
        int q = nblk >> 3, r = nblk & 7;
        int xcd = blk & 7, local = blk >> 3;
        blk = (xcd < r ? xcd * (q + 1) : r * (q + 1) + (xcd - r) * q) + local;
    }
    int base = blk * 32;
    int t = threadIdx.x;
    if (t < 32) {
        int i = base + t;
        pts[t] = (i < N) ? sorted[i] : make_float4(0.f, 0.f, 0.f, __uint_as_float(0u));
    }
    __syncthreads();
    if (t < 128 && (t & 3) < 3) {   // one thread per (point, plane)
        int pt = t >> 2, p = t & 3;
        float4 c = pts[pt];
        float gx = (p == 0) ? c.y : c.x;
        float gy = (p == 2) ? c.y : c.z;
        float ci = (p == 0) ? c.x : ((p == 1) ? c.y : c.z);
        float ix = (gx + 1.f) * 127.5f;
        float iy = (gy + 1.f) * 127.5f;
        float x0f = floorf(ix), y0f = floorf(iy);
        float wx = ix - x0f, wy = iy - y0f;
        int x0 = min(max((int)x0f, 0), HWDIM - 1);
        int y0 = min(max((int)y0f, 0), HWDIM - 1);
        int x1 = min(x0 + 1, HWDIM - 1);
        int y1 = min(y0 + 1, HWDIM - 1);
        uint32_t* m = &meta[pt * 40 + p * 13];
        float cv = (ci + 1.f) * 127.5f + 0.5f;
        float bb[9];
#pragma unroll
        for (int r = 0; r < 9; ++r) {
            const float k = 3.14159265358979f * ((float)(1 << r) - 0.5f) * (1.f / 512.f);
            bb[r] = __cosf(cv * k);
        }
#pragma unroll
        for (int j = 0; j < 4; ++j) m[j] = f2h(bb[2 * j]) | (f2h(bb[2 * j + 1]) << 16);
        m[4] = __float_as_uint(bb[8]);
        m[5] = __float_as_uint((1.f - wx) * (1.f - wy));
        m[6] = __float_as_uint(wx * (1.f - wy));
        m[7] = __float_as_uint((1.f - wx) * wy);
        m[8] = __float_as_uint(wx * wy);
        m[9]  = (uint32_t)(y0 * HWDIM + x0) * 256u;
        m[10] = (uint32_t)(y0 * HWDIM + x1) * 256u;
        m[11] = (uint32_t)(y1 * HWDIM + x0) * 256u;
        m[12] = (uint32_t)(y1 * HWDIM + x1) * 256u;
    }
    __syncthreads();
    int cc = t & 15, slot = t >> 4;
    const char* Ab = (const char*)A;
    const char* Bb = (const char*)B;
    const uint32_t bofs = ((uint32_t)(cc >> 1) << 2);
#pragma unroll
    for (int half = 0; half < 2; ++half) {
        int pt = slot + half * 16;
        int gi = base + pt;
        float acc = 0.f;
#pragma unroll
        for (int p = 0; p < 3; ++p) {
            const uint32_t* m = &meta[pt * 40 + p * 13];
            half2_t b01 = u2h(m[0]), b23 = u2h(m[1]), b45 = u2h(m[2]), b67 = u2h(m[3]);
            float b8 = __uint_as_float(m[4]);
            const char* Apl = Ab + (size_t)p * ((size_t)POSN * 256);
            const char* Bpl = Bb + (size_t)p * ((size_t)POSN * 32);
            float ps = 0.f;
#pragma unroll
            for (int k = 0; k < 4; ++k) {
                uint32_t ob = m[9 + k];
                uint4 a = *(const uint4*)(Apl + ob + cc * 16);    // 16 lanes read 256B contiguous
                uint32_t bw = *(const uint32_t*)(Bpl + (ob >> 3) + bofs);
                float v8 = h2f((cc & 1) ? (bw >> 16) : (bw & 0xffffu));
                float s = b8 * v8;
                s = DOT2(u2h(a.x), b01, s);
                s = DOT2(u2h(a.y), b23, s);
                s = DOT2(u2h(a.z), b45, s);
                s = DOT2(u2h(a.w), b67, s);
                ps = fmaf(__uint_as_float(m[5 + k]), s, ps);
            }
            acc += ps;
        }
        if (gi < N) {
            uint32_t n = __float_as_uint(pts[pt].w);
            out[(size_t)n * CHN + cc] = 2.f * acc;
        }
    }
}

// ---------- fallback: direct gather from (C,H,W) f32 ----------
__global__ __launch_bounds__(256) void triplane_direct(const float* __restrict__ coords,
                                                       const float* __restrict__ Pu,
                                                       const float* __restrict__ Pv,
                                                       const float* __restrict__ Pw,
                                                       float* __restrict__ out, int N) {
    int tid = blockIdx.x * blockDim.x + threadIdx.x;
    int n = tid >> 4;
    if (n >= N) return;
    int cc = tid & 15;
    float c0 = coords[3 * n + 0];
    float c1 = coords[3 * n + 1];
    float c2 = coords[3 * n + 2];
    float acc = 0.f;
#pragma unroll
    for (int p = 0; p < 3; ++p) {
        const float* P = (p == 0) ? Pu : ((p == 1) ? Pv : Pw);
        float gx = (p == 0) ? c1 : c0;
        float gy = (p == 2) ? c1 : c2;
        float ci = (p == 0) ? c0 : ((p == 1) ? c1 : c2);
        float ix = (gx + 1.f) * 127.5f;
        float iy = (gy + 1.f) * 127.5f;
        float x0f = floorf(ix), y0f = floorf(iy);
        float wx = ix - x0f, wy = iy - y0f;
        int x0 = min(max((int)x0f, 0), HWDIM - 1);
        int y0 = min(max((int)y0f, 0), HWDIM - 1);
        int x1 = min(x0 + 1, HWDIM - 1);
        int y1 = min(y0 + 1, HWDIM - 1);
        float cv = (ci + 1.f) * 127.5f + 0.5f;
        float w00 = (1.f - wx) * (1.f - wy), w01 = wx * (1.f - wy);
        float w10 = (1.f - wx) * wy, w11 = wx * wy;
        int p00 = y0 * HWDIM + x0, p01 = y0 * HWDIM + x1;
        int p10 = y1 * HWDIM + x0, p11 = y1 * HWDIM + x1;
#pragma unroll
        for (int r = 0; r < RF; ++r) {
            const float k = 3.14159265358979f * ((float)(1 << r) - 0.5f) / 512.f;
            float b = __cosf(cv * k);
            const float* Pc = P + (size_t)(cc * RF + r) * POSN;
            float v = w00 * Pc[p00] + w01 * Pc[p01] + w10 * Pc[p10] + w11 * Pc[p11];
            acc = fmaf(b, v, acc);
        }
    }
    out[(size_t)n * CHN + cc] = 2.f * acc;
}

extern "C" void kernel_launch(void* const* d_in, const int* in_sizes, int n_in,
                              void* d_out, int out_size, void* d_ws, size_t ws_size,
                              hipStream_t stream) {
    const float* coords = (const float*)d_in[0];
    const float* Pu = (const float*)d_in[1];
    const float* Pv = (const float*)d_in[2];
    const float* Pw = (const float*)d_in[3];
    float* out = (float*)d_out;
    int N = in_sizes[0] / 3;

    size_t offA = 0;
    size_t szA = (size_t)3 * POSN * CHN * sizeof(uint4);        // 48 MB
    size_t offB = offA + szA;
    size_t szB = (size_t)3 * POSN * 8 * sizeof(uint32_t);       // 6 MB
    size_t offS = offB + szB;
    size_t szS = (size_t)N * sizeof(float4);                    // 8 MB @ N=524288
    size_t offH = offS + szS;
    size_t szH = (size_t)NBINS * sizeof(uint32_t);              // 128 KB
    size_t need = offH + szH;

    if (ws_size >= need) {
        char* ws = (char*)d_ws;
        uint4* A = (uint4*)(ws + offA);
        uint32_t* B = (uint32_t*)(ws + offB);
        float4* sorted = (float4*)(ws + offS);
        uint32_t* hist = (uint32_t*)(ws + offH);

        int tblk = (3 * POSN) / TPOS;                // 3072 pack tiles (64 pos each)
        int s1 = tblk / 3;                           // 1024
        int s2 = tblk / 3;                           // 1024
        int s3 = tblk - s1 - s2;                     // 1024
        int hblk = (N + 255) / 256;                  // 2048

        hipMemsetAsync(hist, 0, szH, stream);
        fuse_hist<<<s1 + hblk, 256, 0, stream>>>(Pu, Pv, Pw, A, B, coords, hist, N, s1, 0);
        fuse_scan<<<1 + s2, 256, 0, stream>>>(Pu, Pv, Pw, A, B, hist, s2, s1);
        fuse_scatter<<<s3 + hblk, 256, 0, stream>>>(Pu, Pv, Pw, A, B, coords, hist, sorted,
                                                    N, s3, s1 + s2);
        int nblk = (N + 31) / 32;                    // 16384
        triplane_f16v2<<<nblk, 256, 0, stream>>>(sorted, A, B, out, N, nblk);
    } else {
        int threads = N * CHN;
        triplane_direct<<<(threads + 255) / 256, 256, 0, stream>>>(coords, Pu, Pv, Pw, out, N);
    }
}